// Round 1
// baseline (1085.911 us; speedup 1.0000x reference)
//
#include <hip/hip_runtime.h>
#include <stdint.h>

#define Bsz 4
#define Nn 4096
#define Dd 512

// ---------------- K1: row inverse norms ----------------
__global__ __launch_bounds__(128) void norms_kernel(const float* __restrict__ x,
                                                    float* __restrict__ rinv) {
  int row = blockIdx.x;   // B*N rows
  int t = threadIdx.x;    // 128 threads, one float4 each (512 floats)
  const float4* xr = (const float4*)(x + (size_t)row * Dd);
  float4 v = xr[t];
  float s = v.x * v.x + v.y * v.y + v.z * v.z + v.w * v.w;
  for (int o = 32; o > 0; o >>= 1) s += __shfl_down(s, o, 64);
  __shared__ float ls[2];
  if ((t & 63) == 0) ls[t >> 6] = s;
  __syncthreads();
  if (t == 0) {
    float nrm = sqrtf(ls[0] + ls[1]);
    rinv[row] = 1.0f / fmaxf(nrm, 1e-12f);
  }
}

// ---------------- K2: symmetric fp32 GEMM (upper-triangle tiles) ----------------
#define BT 128
#define BKC 16
#define LDA (BT + 4)   // 132 floats: keeps float4 LDS reads 16B-aligned, 2-way conflict max

__global__ __launch_bounds__(256) void gemm_sym(const float* __restrict__ x,
                                                const float* __restrict__ rinv,
                                                float* __restrict__ out) {
  __shared__ __align__(16) float As[BKC][LDA];
  __shared__ __align__(16) float Bs[BKC][LDA];
  int b = blockIdx.y;
  int p = blockIdx.x;             // 0..527 (T=32 -> 32*33/2 tile pairs)
  const int T = Nn / BT;          // 32
  int ti = 0;
  while (p >= T - ti) { p -= T - ti; ti++; }
  int tj = ti + p;
  int ri0 = ti * BT, rj0 = tj * BT;
  int tid = threadIdx.x;
  int tx = tid & 15, ty = tid >> 4;
  const float* xb = x + (size_t)b * Nn * Dd;

  float acc[8][8];
#pragma unroll
  for (int u = 0; u < 8; u++)
#pragma unroll
    for (int v = 0; v < 8; v++) acc[u][v] = 0.0f;

  for (int k0 = 0; k0 < Dd; k0 += BKC) {
    __syncthreads();
#pragma unroll
    for (int h = 0; h < 2; h++) {
      int q = tid + h * 256;          // 512 float4 units per tile
      int r = q >> 2;                 // 0..127
      int kc = (q & 3) << 2;          // 0,4,8,12
      float4 a = *(const float4*)(xb + (size_t)(ri0 + r) * Dd + k0 + kc);
      As[kc + 0][r] = a.x; As[kc + 1][r] = a.y; As[kc + 2][r] = a.z; As[kc + 3][r] = a.w;
      float4 bb = *(const float4*)(xb + (size_t)(rj0 + r) * Dd + k0 + kc);
      Bs[kc + 0][r] = bb.x; Bs[kc + 1][r] = bb.y; Bs[kc + 2][r] = bb.z; Bs[kc + 3][r] = bb.w;
    }
    __syncthreads();
#pragma unroll
    for (int kk = 0; kk < BKC; kk++) {
      float a[8], bb[8];
      *(float4*)&a[0]  = *(const float4*)&As[kk][ty * 8];
      *(float4*)&a[4]  = *(const float4*)&As[kk][ty * 8 + 4];
      *(float4*)&bb[0] = *(const float4*)&Bs[kk][tx * 8];
      *(float4*)&bb[4] = *(const float4*)&Bs[kk][tx * 8 + 4];
#pragma unroll
      for (int u = 0; u < 8; u++)
#pragma unroll
        for (int v = 0; v < 8; v++)
          acc[u][v] = fmaf(a[u], bb[v], acc[u][v]);
    }
  }

  float ra[8], rb[8];
#pragma unroll
  for (int u = 0; u < 8; u++) ra[u] = rinv[b * Nn + ri0 + ty * 8 + u];
#pragma unroll
  for (int v = 0; v < 8; v++) rb[v] = rinv[b * Nn + rj0 + tx * 8 + v];

  float* ob = out + (size_t)b * Nn * Nn;
  // primary (upper) write
#pragma unroll
  for (int u = 0; u < 8; u++) {
    size_t gr = (size_t)(ri0 + ty * 8 + u) * Nn + rj0 + tx * 8;
#pragma unroll
    for (int v = 0; v < 8; v += 4) {
      float4 w;
      w.x = acc[u][v + 0] * ra[u] * rb[v + 0];
      w.y = acc[u][v + 1] * ra[u] * rb[v + 1];
      w.z = acc[u][v + 2] * ra[u] * rb[v + 2];
      w.w = acc[u][v + 3] * ra[u] * rb[v + 3];
      *(float4*)(ob + gr + v) = w;
    }
  }
  // mirror write (bitwise-identical expression => bitwise-identical values)
  if (ti != tj) {
#pragma unroll
    for (int v = 0; v < 8; v++) {
      size_t gr = (size_t)(rj0 + tx * 8 + v) * Nn + ri0 + ty * 8;
#pragma unroll
      for (int u = 0; u < 8; u += 4) {
        float4 w;
        w.x = acc[u + 0][v] * ra[u + 0] * rb[v];
        w.y = acc[u + 1][v] * ra[u + 1] * rb[v];
        w.z = acc[u + 2][v] * ra[u + 2] * rb[v];
        w.w = acc[u + 3][v] * ra[u + 3] * rb[v];
        *(float4*)(ob + gr + u) = w;
      }
    }
  }
}

// ---------------- K3: per-row exact rank-32 threshold + keep bitmask ----------------
__global__ __launch_bounds__(256) void select_kernel(const float* __restrict__ sim,
                                                     uint32_t* __restrict__ bm) {
  int row = blockIdx.x;   // B*N rows
  int t = threadIdx.x;    // 256
  const float* srow = sim + (size_t)row * Nn;
  __shared__ uint32_t su[Nn];     // 16 KB sortable-int view of the row
  __shared__ uint32_t red[4];
  __shared__ uint32_t lmask[128];
  __shared__ int eqlist[64];
  __shared__ int eqcnt;

  for (int i = 0; i < 16; i++) {
    int c = i * 256 + t;
    uint32_t b = __float_as_uint(srow[c]);
    su[c] = (b & 0x80000000u) ? ~b : (b | 0x80000000u);
  }
  if (t < 128) lmask[t] = 0;
  if (t == 0) eqcnt = 0;
  __syncthreads();

  // binary search for minimal S with count(su > S) <= 31  => S == sortable(v32)
  uint32_t lo = 0, hi = 0xFFFFFFFFu;
  while (lo < hi) {
    uint32_t mid = lo + ((hi - lo) >> 1);
    int cnt = 0;
    for (int i = 0; i < 16; i++) cnt += (su[i * 256 + t] > mid) ? 1 : 0;
    for (int o = 32; o > 0; o >>= 1) cnt += __shfl_down(cnt, o, 64);
    if ((t & 63) == 0) red[t >> 6] = (uint32_t)cnt;
    __syncthreads();
    uint32_t total = red[0] + red[1] + red[2] + red[3];
    if (total <= 31) hi = mid; else lo = mid + 1;
    __syncthreads();
  }
  uint32_t S = lo;

  // build keep pattern for columns [t*16, t*16+16); collect ties
  uint32_t pat = 0;
  int cnt = 0;
  for (int i = 0; i < 16; i++) {
    uint32_t v = su[t * 16 + i];
    if (v > S) { pat |= (1u << i); cnt++; }
    else if (v == S) {
      int slot = atomicAdd(&eqcnt, 1);
      if (slot < 64) eqlist[slot] = t * 16 + i;
    }
  }
  for (int o = 32; o > 0; o >>= 1) cnt += __shfl_down(cnt, o, 64);
  if ((t & 63) == 0) red[t >> 6] = (uint32_t)cnt;
  atomicOr(&lmask[t >> 1], pat << ((t & 1) * 16));
  __syncthreads();

  if (t == 0) {
    int c = (int)(red[0] + red[1] + red[2] + red[3]);   // strictly greater than v32
    int need = 32 - c;                                   // ties to keep (lowest index first)
    int d = eqcnt; if (d > 64) d = 64;
    for (int s = 0; s < need; s++) {
      int best = 0x7FFFFFFF, bi = -1;
      for (int i = 0; i < d; i++) {
        int idx = eqlist[i];
        if (idx >= 0 && idx < best) { best = idx; bi = i; }
      }
      if (bi < 0) break;
      eqlist[bi] = -1;
      lmask[best >> 5] |= (1u << (best & 31));
    }
  }
  __syncthreads();
  if (t < 128) bm[(size_t)row * 128 + t] = lmask[t];
}

// ---------------- K4: masked symmetrize, in place ----------------
__global__ __launch_bounds__(256) void finalize_kernel(float* __restrict__ out,
                                                       const uint32_t* __restrict__ bm) {
  __shared__ float Tt[64][65];
  __shared__ uint32_t kA[64][2], kB[64][2];
  int b = blockIdx.y;
  int p = blockIdx.x;             // 0..2079 (T=64)
  const int T = Nn / 64;
  int ti = 0;
  while (p >= T - ti) { p -= T - ti; ti++; }
  int tj = ti + p;
  int ri0 = ti * 64, rj0 = tj * 64;
  int t = threadIdx.x;
  const uint32_t* bmb = bm + (size_t)b * Nn * 128;
  if (t < 128) {
    kA[t >> 1][t & 1] = bmb[(size_t)(ri0 + (t >> 1)) * 128 + (rj0 >> 5) + (t & 1)];
  } else {
    int tt = t - 128;
    kB[tt >> 1][tt & 1] = bmb[(size_t)(rj0 + (tt >> 1)) * 128 + (ri0 >> 5) + (tt & 1)];
  }
  __syncthreads();
  float* ob = out + (size_t)b * Nn * Nn;
#pragma unroll
  for (int k = 0; k < 16; k++) {
    int e = k * 256 + t;
    int nl = e >> 6, ml = e & 63;
    size_t addr = (size_t)(ri0 + nl) * Nn + rj0 + ml;
    float s = ob[addr];
    uint32_t ba = (kA[nl][ml >> 5] >> (ml & 31)) & 1u;
    uint32_t bb = (kB[ml][nl >> 5] >> (nl & 31)) & 1u;
    float v = 0.5f * s * (float)(ba + bb);
    ob[addr] = v;
    Tt[ml][nl] = v;
  }
  if (ti != tj) {
    __syncthreads();
#pragma unroll
    for (int k = 0; k < 16; k++) {
      int e = k * 256 + t;
      int nl = e >> 6, ml = e & 63;
      ob[(size_t)(rj0 + nl) * Nn + ri0 + ml] = Tt[nl][ml];
    }
  }
}

extern "C" void kernel_launch(void* const* d_in, const int* in_sizes, int n_in,
                              void* d_out, int out_size, void* d_ws, size_t ws_size,
                              hipStream_t stream) {
  const float* x = (const float*)d_in[0];
  float* out = (float*)d_out;
  float* rinv = (float*)d_ws;                                  // 64 KB
  uint32_t* bm = (uint32_t*)((char*)d_ws + 65536);             // 8 MB bitmask

  norms_kernel<<<Bsz * Nn, 128, 0, stream>>>(x, rinv);
  dim3 g2(528, Bsz);
  gemm_sym<<<g2, 256, 0, stream>>>(x, rinv, out);
  select_kernel<<<Bsz * Nn, 256, 0, stream>>>(out, bm);
  dim3 g4(2080, Bsz);
  finalize_kernel<<<g4, 256, 0, stream>>>(out, bm);
}